// Round 5
// baseline (3467.329 us; speedup 1.0000x reference)
//
#include <hip/hip_runtime.h>

// EdgeNetwork fused MLP on MI355X — register-chained swapped-operand MFMA (bf16 hi/lo split).
// B=8, N=50000, E=200000, D=16, H=128.
// Every layer computes D = W (A-role) x X (B-role) with mfma_f32_16x16x32_bf16, so the
// verified C/D layout (col=lane&15=edge, row=4*(lane>>4)+reg=feature) IS the next layer's
// B-fragment layout: activations never leave registers. fp32 emulated as bf16_hi+bf16_lo,
// 3 MFMAs per product (hh, hl, lh; lo*lo dropped ~2^-17 rel).
// Weights (all 3 layers, hi/lo) staged ONCE per persistent block into 149KB dynamic LDS,
// XOR-swizzled ((j&7)<<4) for minimal-bank-pass ds_read_b128 W-fragment loads.
// Per wave: 32 edges (2 col-blocks sharing each W-frag), all 128 features (LN = shfl_xor 16,32).
// No __syncthreads in the persistent loop — waves drift, overlapping MFMA and VALU pipes.
//
// R3 fix (unbenched due to GPU timeouts; carried): harness delivers integer inputs as int32
// ("integer -> const int*") — int64 reads consumed 2x the buffer -> OOB gather -> SIGABRT.
// Now: const int* + int2 loads + defensive index clamp (any residual dtype surprise becomes
// an absmax failure, not a core dump).

#define DEV __device__ __forceinline__

constexpr int NB = 8, NN = 50000, NE = 200000, DD = 16, HH = 128;
constexpr int TILE = 256;                  // edges per block-tile (8 waves x 32)
constexpr int BDIM = 512;
constexpr int GRID = 256;                  // persistent: 1 block per CU
constexpr int NTILE = NB * NE / TILE;      // 6250 exactly
constexpr float LNEPS = 1e-5f;

typedef __attribute__((ext_vector_type(8))) short short8v;  // 8 bf16 (4 VGPRs) MFMA operand
typedef __attribute__((ext_vector_type(4))) float f32x4;    // MFMA accumulator

// LDS carve (shorts): W1 hi|lo 128x32 each (8KB x2), W2 hi|lo 128x128 (32KB x2), W3 same,
// then fp32 params: [3 layers][b,g,be][128] + W4[128] + b4. Total 152580 B < 160KB.
constexpr int W1_HALF = 128 * 32;
constexpr int W2_HALF = 128 * 128;
constexpr size_t SMEM_BYTES = (size_t)(2 * W1_HALF + 4 * W2_HALF) * sizeof(short)
                            + (size_t)(10 * HH + 1) * sizeof(float);

DEV void bsplit(float v, short& h, short& l) {
    unsigned u  = __builtin_bit_cast(unsigned, v);
    unsigned hb = (u + 0x8000u) & 0xFFFF0000u;      // bf16 round-to-nearest (half-up)
    float hf    = __builtin_bit_cast(float, hb);
    h = (short)(hb >> 16);
    float lf    = v - hf;                            // exact residual
    unsigned ul = __builtin_bit_cast(unsigned, lf);
    l = (short)((ul + 0x8000u) >> 16);
}

DEV f32x4 mf(short8v a, short8v b, f32x4 c) {
    return __builtin_amdgcn_mfma_f32_16x16x32_bf16(a, b, c, 0, 0, 0);
}

DEV float tanh_fast(float x) { return 1.0f - 2.0f / (1.0f + __expf(2.0f * x)); }

extern "C" __global__ __launch_bounds__(BDIM, 2) void edge_mlp(
    const float* __restrict__ nodes, const int* __restrict__ edges,
    const float* __restrict__ W1, const float* __restrict__ b1,
    const float* __restrict__ g1, const float* __restrict__ be1,
    const float* __restrict__ W2, const float* __restrict__ b2,
    const float* __restrict__ g2, const float* __restrict__ be2,
    const float* __restrict__ W3, const float* __restrict__ b3,
    const float* __restrict__ g3, const float* __restrict__ be3,
    const float* __restrict__ W4, const float* __restrict__ b4,
    float* __restrict__ out) {

    extern __shared__ char smem[];
    short* W1h = (short*)smem;
    short* W1l = W1h + W1_HALF;
    short* W2h = W1l + W1_HALF;
    short* W2l = W2h + W2_HALF;
    short* W3h = W2l + W2_HALF;
    short* W3l = W3h + W2_HALF;
    float* P   = (float*)(W3l + W2_HALF);   // [0..2]b1g1be1 [3..5]L2 [6..8]L3 [9]W4 [10*128]b4

    const int tid = threadIdx.x;

    // ---- one-time weight staging (persistent block) ----
    // assumed MFMA k-map (A and B identical): slot i of lane-group g holds
    // k = 32c + 16*(i>>2) + 4g + (i&3); storage index kk = 32c + 8g + 4h2 + e.
    for (int i = tid; i < 32 * 128; i += BDIM) {
        int k = i >> 7, j = i & 127;
        short h, l; bsplit(W1[i], h, l);
        int kk = 8 * ((k >> 2) & 3) + 4 * (k >> 4) + (k & 3);
        W1h[j * 32 + kk] = h;                       // 64B rows: minimal bank passes
        W1l[j * 32 + kk] = l;
    }
    for (int i = tid; i < 128 * 128; i += BDIM) {
        int k = i >> 7, j = i & 127;
        int kk = 32 * (k >> 5) + 8 * ((k >> 2) & 3) + 4 * ((k >> 4) & 1) + (k & 3);
        unsigned off = (unsigned)(j * 256 + kk * 2) ^ ((unsigned)(j & 7) << 4); // byte, swizzled
        short h, l;
        bsplit(W2[i], h, l);
        *(short*)((char*)W2h + off) = h;  *(short*)((char*)W2l + off) = l;
        bsplit(W3[i], h, l);
        *(short*)((char*)W3h + off) = h;  *(short*)((char*)W3l + off) = l;
    }
    if (tid < HH) {
        P[0*HH+tid] = b1[tid]; P[1*HH+tid] = g1[tid]; P[2*HH+tid] = be1[tid];
        P[3*HH+tid] = b2[tid]; P[4*HH+tid] = g2[tid]; P[5*HH+tid] = be2[tid];
        P[6*HH+tid] = b3[tid]; P[7*HH+tid] = g3[tid]; P[8*HH+tid] = be3[tid];
        P[9*HH+tid] = W4[tid];
        if (tid == 0) P[10*HH] = b4[0];
    }
    __syncthreads();

    const int lane = tid & 63;
    const int wv   = tid >> 6;      // wave 0..7
    const int m    = lane & 15;     // A-role: feature row within 16-tile; B-role: edge col
    const int g    = lane >> 4;     // 0..3 k-slot group

    // epilogue: bias + LayerNorm + tanh, in place on acc (f32)
    auto EPI = [&](const float* PB, f32x4 (&A)[2][8]) {
        #pragma unroll
        for (int jt = 0; jt < 8; ++jt) {
            const f32x4 bj = *(const f32x4*)&PB[16 * jt + 4 * g];
            #pragma unroll
            for (int cb = 0; cb < 2; ++cb) {
                A[cb][jt][0] += bj[0]; A[cb][jt][1] += bj[1];
                A[cb][jt][2] += bj[2]; A[cb][jt][3] += bj[3];
            }
        }
        #pragma unroll
        for (int cb = 0; cb < 2; ++cb) {
            float s = 0.f, s2 = 0.f;
            #pragma unroll
            for (int jt = 0; jt < 8; ++jt)
                #pragma unroll
                for (int p = 0; p < 4; ++p) {
                    float v = A[cb][jt][p]; s += v; s2 = fmaf(v, v, s2);
                }
            s  += __shfl_xor(s, 16);  s2 += __shfl_xor(s2, 16);
            s  += __shfl_xor(s, 32);  s2 += __shfl_xor(s2, 32);
            const float mu  = s * (1.f / HH);
            const float var = fmaf(-mu, mu, s2 * (1.f / HH));
            const float rin = rsqrtf(var + LNEPS);
            #pragma unroll
            for (int jt = 0; jt < 8; ++jt) {
                const f32x4 gj = *(const f32x4*)&PB[HH     + 16 * jt + 4 * g];
                const f32x4 bj = *(const f32x4*)&PB[2 * HH + 16 * jt + 4 * g];
                #pragma unroll
                for (int p = 0; p < 4; ++p) {
                    float v = (A[cb][jt][p] - mu) * rin * gj[p] + bj[p];
                    A[cb][jt][p] = tanh_fast(v);
                }
            }
        }
    };

    // acc (post-act) -> next layer's B-fragments: frag[i=4h2+e] = A[cb][2c+h2][e]
    auto TOFRAGS = [&](const f32x4 (&A)[2][8], short8v (&fh)[2][4], short8v (&fl)[2][4]) {
        #pragma unroll
        for (int cb = 0; cb < 2; ++cb)
            #pragma unroll
            for (int c = 0; c < 4; ++c) {
                short8v vh, vl; short h, l;
                bsplit(A[cb][2*c  ][0], h, l); vh[0] = h; vl[0] = l;
                bsplit(A[cb][2*c  ][1], h, l); vh[1] = h; vl[1] = l;
                bsplit(A[cb][2*c  ][2], h, l); vh[2] = h; vl[2] = l;
                bsplit(A[cb][2*c  ][3], h, l); vh[3] = h; vl[3] = l;
                bsplit(A[cb][2*c+1][0], h, l); vh[4] = h; vl[4] = l;
                bsplit(A[cb][2*c+1][1], h, l); vh[5] = h; vl[5] = l;
                bsplit(A[cb][2*c+1][2], h, l); vh[6] = h; vl[6] = l;
                bsplit(A[cb][2*c+1][3], h, l); vh[7] = h; vl[7] = l;
                fh[cb][c] = vh; fl[cb][c] = vl;
            }
    };

    // K=128 GEMM layer: 4 chunks x 8 j-tiles x 2 col-blocks x 3 split-MFMAs
    auto GEMM = [&](const short* Wh, const short* Wl,
                    const short8v (&fh)[2][4], const short8v (&fl)[2][4],
                    f32x4 (&A)[2][8]) {
        #pragma unroll
        for (int cb = 0; cb < 2; ++cb)
            #pragma unroll
            for (int jt = 0; jt < 8; ++jt) A[cb][jt] = (f32x4){0.f, 0.f, 0.f, 0.f};
        #pragma unroll
        for (int c = 0; c < 4; ++c) {
            #pragma unroll
            for (int jt = 0; jt < 8; ++jt) {
                const int jr = 16 * jt + m;
                const unsigned off = (unsigned)(jr * 256 + (32 * c + 8 * g) * 2)
                                   ^ ((unsigned)(jr & 7) << 4);
                const short8v wh = *(const short8v*)((const char*)Wh + off);
                const short8v wl = *(const short8v*)((const char*)Wl + off);
                #pragma unroll
                for (int cb = 0; cb < 2; ++cb) {
                    f32x4 a = A[cb][jt];
                    a = mf(wl, fh[cb][c], a);
                    a = mf(wh, fl[cb][c], a);
                    a = mf(wh, fh[cb][c], a);
                    A[cb][jt] = a;
                }
            }
        }
    };

    // ---- persistent tile loop (no barriers; waves drift and overlap pipes) ----
    for (int t = blockIdx.x; t < NTILE; t += GRID) {
        const int ebase = t * TILE + wv * 32;

        // gather -> layer-1 B-frags, register-direct
        // (slot i<4: endpoint0 feature 4g+(i&3); slot i>=4: endpoint1)
        short8v x1h[2], x1l[2];
        #pragma unroll
        for (int cb = 0; cb < 2; ++cb) {
            const int e = ebase + cb * 16 + m;
            const int2 nv = *(const int2*)(edges + 2 * (size_t)e);   // int32 pairs per harness
            const int b = e / NE;
            const int n0 = min(max(nv.x, 0), NN - 1);                // defensive: fault->absmax
            const int n1 = min(max(nv.y, 0), NN - 1);
            const f32x4 f0 = *(const f32x4*)(nodes + (size_t)(b * NN + n0) * DD + 4 * g);
            const f32x4 f1 = *(const f32x4*)(nodes + (size_t)(b * NN + n1) * DD + 4 * g);
            short8v vh, vl; short h, l;
            bsplit(f0[0], h, l); vh[0] = h; vl[0] = l;
            bsplit(f0[1], h, l); vh[1] = h; vl[1] = l;
            bsplit(f0[2], h, l); vh[2] = h; vl[2] = l;
            bsplit(f0[3], h, l); vh[3] = h; vl[3] = l;
            bsplit(f1[0], h, l); vh[4] = h; vl[4] = l;
            bsplit(f1[1], h, l); vh[5] = h; vl[5] = l;
            bsplit(f1[2], h, l); vh[6] = h; vl[6] = l;
            bsplit(f1[3], h, l); vh[7] = h; vl[7] = l;
            x1h[cb] = vh; x1l[cb] = vl;
        }

        // layer 1 (K=32, one chunk)
        f32x4 acc[2][8];
        #pragma unroll
        for (int jt = 0; jt < 8; ++jt) {
            const int jr = 16 * jt + m;
            const short8v wh = *(const short8v*)&W1h[jr * 32 + 8 * g];
            const short8v wl = *(const short8v*)&W1l[jr * 32 + 8 * g];
            #pragma unroll
            for (int cb = 0; cb < 2; ++cb) {
                f32x4 a = (f32x4){0.f, 0.f, 0.f, 0.f};
                a = mf(wl, x1h[cb], a);
                a = mf(wh, x1l[cb], a);
                a = mf(wh, x1h[cb], a);
                acc[cb][jt] = a;
            }
        }

        short8v xh[2][4], xl[2][4];
        EPI(P + 0 * 3 * HH, acc);
        TOFRAGS(acc, xh, xl);
        GEMM(W2h, W2l, xh, xl, acc);      // layer 2
        EPI(P + 1 * 3 * HH, acc);
        TOFRAGS(acc, xh, xl);
        GEMM(W3h, W3l, xh, xl, acc);      // layer 3
        EPI(P + 2 * 3 * HH, acc);

        // layer 4: per-lane partial dot over its 32 features, reduce over g-groups, sigmoid
        const float bb4 = P[10 * HH];
        #pragma unroll
        for (int cb = 0; cb < 2; ++cb) {
            float s = 0.f;
            #pragma unroll
            for (int jt = 0; jt < 8; ++jt) {
                const f32x4 w4v = *(const f32x4*)&P[9 * HH + 16 * jt + 4 * g];
                s = fmaf(acc[cb][jt][0], w4v[0], s);
                s = fmaf(acc[cb][jt][1], w4v[1], s);
                s = fmaf(acc[cb][jt][2], w4v[2], s);
                s = fmaf(acc[cb][jt][3], w4v[3], s);
            }
            s += __shfl_xor(s, 16);
            s += __shfl_xor(s, 32);
            if (g == 0) out[ebase + cb * 16 + m] = 1.f / (1.f + __expf(-(s + bb4)));
        }
    }
}

extern "C" void kernel_launch(void* const* d_in, const int* in_sizes, int n_in,
                              void* d_out, int out_size, void* d_ws, size_t ws_size,
                              hipStream_t stream) {
    (void)in_sizes; (void)n_in; (void)d_ws; (void)ws_size; (void)out_size;
    const float* nodes = (const float*)d_in[0];
    const int*   edges = (const int*)d_in[1];     // harness: integer inputs arrive as int32
    const float *W1 = (const float*)d_in[2],  *b1  = (const float*)d_in[3];
    const float *g1 = (const float*)d_in[4],  *be1 = (const float*)d_in[5];
    const float *W2 = (const float*)d_in[6],  *b2  = (const float*)d_in[7];
    const float *g2 = (const float*)d_in[8],  *be2 = (const float*)d_in[9];
    const float *W3 = (const float*)d_in[10], *b3  = (const float*)d_in[11];
    const float *g3 = (const float*)d_in[12], *be3 = (const float*)d_in[13];
    const float *W4 = (const float*)d_in[14], *b4  = (const float*)d_in[15];
    float* out = (float*)d_out;

    // Unconditional (no static guards per harness rules): host-side attribute set,
    // not stream-ordered, safe under graph capture. Required for >64KB dynamic LDS.
    hipFuncSetAttribute(reinterpret_cast<const void*>(&edge_mlp),
                        hipFuncAttributeMaxDynamicSharedMemorySize, (int)SMEM_BYTES);

    edge_mlp<<<GRID, BDIM, SMEM_BYTES, stream>>>(nodes, edges,
                                                 W1, b1, g1, be1,
                                                 W2, b2, g2, be2,
                                                 W3, b3, g3, be3,
                                                 W4, b4, out);
}

// Round 6
// 3464.382 us; speedup vs baseline: 1.0009x; 1.0009x over previous
//
#include <hip/hip_runtime.h>

// EdgeNetwork fused MLP on MI355X — register-chained swapped-operand MFMA (bf16 hi/lo split).
// B=8, N=50000, E=200000, D=16, H=128.
// Every layer computes D = W (A-role) x X (B-role) with mfma_f32_16x16x32_bf16, so the
// verified C/D layout (col=lane&15=edge, row=4*(lane>>4)+reg=feature) IS the next layer's
// B-fragment layout: activations never leave registers. fp32 emulated as bf16_hi+bf16_lo,
// 3 MFMAs per product (hh, hl, lh; lo*lo dropped ~2^-17 rel).
// Weights (all 3 layers, hi/lo) staged ONCE per persistent block into 149KB dynamic LDS,
// XOR-swizzled ((j&7)<<4) for minimal-bank-pass ds_read_b128 W-fragment loads.
// Per wave: 32 edges (2 col-blocks sharing each W-frag), all 128 features (LN = shfl_xor 16,32).
// No __syncthreads in the persistent loop — waves drift, overlapping MFMA and VALU pipes.
//
// R5 fix: __launch_bounds__(512,2) was interpreted as CUDA-style min-BLOCKS-per-CU
// (2 blocks x 8 waves = 4 waves/SIMD) -> VGPR capped at 128 -> ~50 VGPRs of GEMM state
// spilled to scratch and re-filled inside the unrolled loops -> 7.2GB FETCH + 1.2GB WRITE
// of HBM scratch traffic -> memory-bound at 3.45ms (dur == hbm_bytes/2.47TB/s).
// Now (512,1): 1 block/CU (LDS limits to 1 anyway), VGPR cap 256, demand ~170 fits.

#define DEV __device__ __forceinline__

constexpr int NB = 8, NN = 50000, NE = 200000, DD = 16, HH = 128;
constexpr int TILE = 256;                  // edges per block-tile (8 waves x 32)
constexpr int BDIM = 512;
constexpr int GRID = 256;                  // persistent: 1 block per CU
constexpr int NTILE = NB * NE / TILE;      // 6250 exactly
constexpr float LNEPS = 1e-5f;

typedef __attribute__((ext_vector_type(8))) short short8v;  // 8 bf16 (4 VGPRs) MFMA operand
typedef __attribute__((ext_vector_type(4))) float f32x4;    // MFMA accumulator

// LDS carve (shorts): W1 hi|lo 128x32 each (8KB x2), W2 hi|lo 128x128 (32KB x2), W3 same,
// then fp32 params: [3 layers][b,g,be][128] + W4[128] + b4. Total 152580 B < 160KB.
constexpr int W1_HALF = 128 * 32;
constexpr int W2_HALF = 128 * 128;
constexpr size_t SMEM_BYTES = (size_t)(2 * W1_HALF + 4 * W2_HALF) * sizeof(short)
                            + (size_t)(10 * HH + 1) * sizeof(float);

DEV void bsplit(float v, short& h, short& l) {
    unsigned u  = __builtin_bit_cast(unsigned, v);
    unsigned hb = (u + 0x8000u) & 0xFFFF0000u;      // bf16 round-to-nearest (half-up)
    float hf    = __builtin_bit_cast(float, hb);
    h = (short)(hb >> 16);
    float lf    = v - hf;                            // exact residual
    unsigned ul = __builtin_bit_cast(unsigned, lf);
    l = (short)((ul + 0x8000u) >> 16);
}

DEV f32x4 mf(short8v a, short8v b, f32x4 c) {
    return __builtin_amdgcn_mfma_f32_16x16x32_bf16(a, b, c, 0, 0, 0);
}

DEV float tanh_fast(float x) { return 1.0f - 2.0f / (1.0f + __expf(2.0f * x)); }

extern "C" __global__ __launch_bounds__(BDIM, 1) void edge_mlp(
    const float* __restrict__ nodes, const int* __restrict__ edges,
    const float* __restrict__ W1, const float* __restrict__ b1,
    const float* __restrict__ g1, const float* __restrict__ be1,
    const float* __restrict__ W2, const float* __restrict__ b2,
    const float* __restrict__ g2, const float* __restrict__ be2,
    const float* __restrict__ W3, const float* __restrict__ b3,
    const float* __restrict__ g3, const float* __restrict__ be3,
    const float* __restrict__ W4, const float* __restrict__ b4,
    float* __restrict__ out) {

    extern __shared__ char smem[];
    short* W1h = (short*)smem;
    short* W1l = W1h + W1_HALF;
    short* W2h = W1l + W1_HALF;
    short* W2l = W2h + W2_HALF;
    short* W3h = W2l + W2_HALF;
    short* W3l = W3h + W2_HALF;
    float* P   = (float*)(W3l + W2_HALF);   // [0..2]b1g1be1 [3..5]L2 [6..8]L3 [9]W4 [10*128]b4

    const int tid = threadIdx.x;

    // ---- one-time weight staging (persistent block) ----
    // assumed MFMA k-map (A and B identical): slot i of lane-group g holds
    // k = 32c + 16*(i>>2) + 4g + (i&3); storage index kk = 32c + 8g + 4h2 + e.
    for (int i = tid; i < 32 * 128; i += BDIM) {
        int k = i >> 7, j = i & 127;
        short h, l; bsplit(W1[i], h, l);
        int kk = 8 * ((k >> 2) & 3) + 4 * (k >> 4) + (k & 3);
        W1h[j * 32 + kk] = h;                       // 64B rows: minimal bank passes
        W1l[j * 32 + kk] = l;
    }
    for (int i = tid; i < 128 * 128; i += BDIM) {
        int k = i >> 7, j = i & 127;
        int kk = 32 * (k >> 5) + 8 * ((k >> 2) & 3) + 4 * ((k >> 4) & 1) + (k & 3);
        unsigned off = (unsigned)(j * 256 + kk * 2) ^ ((unsigned)(j & 7) << 4); // byte, swizzled
        short h, l;
        bsplit(W2[i], h, l);
        *(short*)((char*)W2h + off) = h;  *(short*)((char*)W2l + off) = l;
        bsplit(W3[i], h, l);
        *(short*)((char*)W3h + off) = h;  *(short*)((char*)W3l + off) = l;
    }
    if (tid < HH) {
        P[0*HH+tid] = b1[tid]; P[1*HH+tid] = g1[tid]; P[2*HH+tid] = be1[tid];
        P[3*HH+tid] = b2[tid]; P[4*HH+tid] = g2[tid]; P[5*HH+tid] = be2[tid];
        P[6*HH+tid] = b3[tid]; P[7*HH+tid] = g3[tid]; P[8*HH+tid] = be3[tid];
        P[9*HH+tid] = W4[tid];
        if (tid == 0) P[10*HH] = b4[0];
    }
    __syncthreads();

    const int lane = tid & 63;
    const int wv   = tid >> 6;      // wave 0..7
    const int m    = lane & 15;     // A-role: feature row within 16-tile; B-role: edge col
    const int g    = lane >> 4;     // 0..3 k-slot group

    // epilogue: bias + LayerNorm + tanh, in place on acc (f32)
    auto EPI = [&](const float* PB, f32x4 (&A)[2][8]) {
        #pragma unroll
        for (int jt = 0; jt < 8; ++jt) {
            const f32x4 bj = *(const f32x4*)&PB[16 * jt + 4 * g];
            #pragma unroll
            for (int cb = 0; cb < 2; ++cb) {
                A[cb][jt][0] += bj[0]; A[cb][jt][1] += bj[1];
                A[cb][jt][2] += bj[2]; A[cb][jt][3] += bj[3];
            }
        }
        #pragma unroll
        for (int cb = 0; cb < 2; ++cb) {
            float s = 0.f, s2 = 0.f;
            #pragma unroll
            for (int jt = 0; jt < 8; ++jt)
                #pragma unroll
                for (int p = 0; p < 4; ++p) {
                    float v = A[cb][jt][p]; s += v; s2 = fmaf(v, v, s2);
                }
            s  += __shfl_xor(s, 16);  s2 += __shfl_xor(s2, 16);
            s  += __shfl_xor(s, 32);  s2 += __shfl_xor(s2, 32);
            const float mu  = s * (1.f / HH);
            const float var = fmaf(-mu, mu, s2 * (1.f / HH));
            const float rin = rsqrtf(var + LNEPS);
            #pragma unroll
            for (int jt = 0; jt < 8; ++jt) {
                const f32x4 gj = *(const f32x4*)&PB[HH     + 16 * jt + 4 * g];
                const f32x4 bj = *(const f32x4*)&PB[2 * HH + 16 * jt + 4 * g];
                #pragma unroll
                for (int p = 0; p < 4; ++p) {
                    float v = (A[cb][jt][p] - mu) * rin * gj[p] + bj[p];
                    A[cb][jt][p] = tanh_fast(v);
                }
            }
        }
    };

    // acc (post-act) -> next layer's B-fragments: frag[i=4h2+e] = A[cb][2c+h2][e]
    auto TOFRAGS = [&](const f32x4 (&A)[2][8], short8v (&fh)[2][4], short8v (&fl)[2][4]) {
        #pragma unroll
        for (int cb = 0; cb < 2; ++cb)
            #pragma unroll
            for (int c = 0; c < 4; ++c) {
                short8v vh, vl; short h, l;
                bsplit(A[cb][2*c  ][0], h, l); vh[0] = h; vl[0] = l;
                bsplit(A[cb][2*c  ][1], h, l); vh[1] = h; vl[1] = l;
                bsplit(A[cb][2*c  ][2], h, l); vh[2] = h; vl[2] = l;
                bsplit(A[cb][2*c  ][3], h, l); vh[3] = h; vl[3] = l;
                bsplit(A[cb][2*c+1][0], h, l); vh[4] = h; vl[4] = l;
                bsplit(A[cb][2*c+1][1], h, l); vh[5] = h; vl[5] = l;
                bsplit(A[cb][2*c+1][2], h, l); vh[6] = h; vl[6] = l;
                bsplit(A[cb][2*c+1][3], h, l); vh[7] = h; vl[7] = l;
                fh[cb][c] = vh; fl[cb][c] = vl;
            }
    };

    // K=128 GEMM layer: 4 chunks x 8 j-tiles x 2 col-blocks x 3 split-MFMAs
    auto GEMM = [&](const short* Wh, const short* Wl,
                    const short8v (&fh)[2][4], const short8v (&fl)[2][4],
                    f32x4 (&A)[2][8]) {
        #pragma unroll
        for (int cb = 0; cb < 2; ++cb)
            #pragma unroll
            for (int jt = 0; jt < 8; ++jt) A[cb][jt] = (f32x4){0.f, 0.f, 0.f, 0.f};
        #pragma unroll
        for (int c = 0; c < 4; ++c) {
            #pragma unroll
            for (int jt = 0; jt < 8; ++jt) {
                const int jr = 16 * jt + m;
                const unsigned off = (unsigned)(jr * 256 + (32 * c + 8 * g) * 2)
                                   ^ ((unsigned)(jr & 7) << 4);
                const short8v wh = *(const short8v*)((const char*)Wh + off);
                const short8v wl = *(const short8v*)((const char*)Wl + off);
                #pragma unroll
                for (int cb = 0; cb < 2; ++cb) {
                    f32x4 a = A[cb][jt];
                    a = mf(wl, fh[cb][c], a);
                    a = mf(wh, fl[cb][c], a);
                    a = mf(wh, fh[cb][c], a);
                    A[cb][jt] = a;
                }
            }
        }
    };

    // ---- persistent tile loop (no barriers; waves drift and overlap pipes) ----
    for (int t = blockIdx.x; t < NTILE; t += GRID) {
        const int ebase = t * TILE + wv * 32;

        // gather -> layer-1 B-frags, register-direct
        // (slot i<4: endpoint0 feature 4g+(i&3); slot i>=4: endpoint1)
        short8v x1h[2], x1l[2];
        #pragma unroll
        for (int cb = 0; cb < 2; ++cb) {
            const int e = ebase + cb * 16 + m;
            const int2 nv = *(const int2*)(edges + 2 * (size_t)e);   // int32 pairs per harness
            const int b = e / NE;
            const int n0 = min(max(nv.x, 0), NN - 1);                // defensive: fault->absmax
            const int n1 = min(max(nv.y, 0), NN - 1);
            const f32x4 f0 = *(const f32x4*)(nodes + (size_t)(b * NN + n0) * DD + 4 * g);
            const f32x4 f1 = *(const f32x4*)(nodes + (size_t)(b * NN + n1) * DD + 4 * g);
            short8v vh, vl; short h, l;
            bsplit(f0[0], h, l); vh[0] = h; vl[0] = l;
            bsplit(f0[1], h, l); vh[1] = h; vl[1] = l;
            bsplit(f0[2], h, l); vh[2] = h; vl[2] = l;
            bsplit(f0[3], h, l); vh[3] = h; vl[3] = l;
            bsplit(f1[0], h, l); vh[4] = h; vl[4] = l;
            bsplit(f1[1], h, l); vh[5] = h; vl[5] = l;
            bsplit(f1[2], h, l); vh[6] = h; vl[6] = l;
            bsplit(f1[3], h, l); vh[7] = h; vl[7] = l;
            x1h[cb] = vh; x1l[cb] = vl;
        }

        // layer 1 (K=32, one chunk)
        f32x4 acc[2][8];
        #pragma unroll
        for (int jt = 0; jt < 8; ++jt) {
            const int jr = 16 * jt + m;
            const short8v wh = *(const short8v*)&W1h[jr * 32 + 8 * g];
            const short8v wl = *(const short8v*)&W1l[jr * 32 + 8 * g];
            #pragma unroll
            for (int cb = 0; cb < 2; ++cb) {
                f32x4 a = (f32x4){0.f, 0.f, 0.f, 0.f};
                a = mf(wl, x1h[cb], a);
                a = mf(wh, x1l[cb], a);
                a = mf(wh, x1h[cb], a);
                acc[cb][jt] = a;
            }
        }

        short8v xh[2][4], xl[2][4];
        EPI(P + 0 * 3 * HH, acc);
        TOFRAGS(acc, xh, xl);
        GEMM(W2h, W2l, xh, xl, acc);      // layer 2
        EPI(P + 1 * 3 * HH, acc);
        TOFRAGS(acc, xh, xl);
        GEMM(W3h, W3l, xh, xl, acc);      // layer 3
        EPI(P + 2 * 3 * HH, acc);

        // layer 4: per-lane partial dot over its 32 features, reduce over g-groups, sigmoid
        const float bb4 = P[10 * HH];
        #pragma unroll
        for (int cb = 0; cb < 2; ++cb) {
            float s = 0.f;
            #pragma unroll
            for (int jt = 0; jt < 8; ++jt) {
                const f32x4 w4v = *(const f32x4*)&P[9 * HH + 16 * jt + 4 * g];
                s = fmaf(acc[cb][jt][0], w4v[0], s);
                s = fmaf(acc[cb][jt][1], w4v[1], s);
                s = fmaf(acc[cb][jt][2], w4v[2], s);
                s = fmaf(acc[cb][jt][3], w4v[3], s);
            }
            s += __shfl_xor(s, 16);
            s += __shfl_xor(s, 32);
            if (g == 0) out[ebase + cb * 16 + m] = 1.f / (1.f + __expf(-(s + bb4)));
        }
    }
}

extern "C" void kernel_launch(void* const* d_in, const int* in_sizes, int n_in,
                              void* d_out, int out_size, void* d_ws, size_t ws_size,
                              hipStream_t stream) {
    (void)in_sizes; (void)n_in; (void)d_ws; (void)ws_size; (void)out_size;
    const float* nodes = (const float*)d_in[0];
    const int*   edges = (const int*)d_in[1];     // harness: integer inputs arrive as int32
    const float *W1 = (const float*)d_in[2],  *b1  = (const float*)d_in[3];
    const float *g1 = (const float*)d_in[4],  *be1 = (const float*)d_in[5];
    const float *W2 = (const float*)d_in[6],  *b2  = (const float*)d_in[7];
    const float *g2 = (const float*)d_in[8],  *be2 = (const float*)d_in[9];
    const float *W3 = (const float*)d_in[10], *b3  = (const float*)d_in[11];
    const float *g3 = (const float*)d_in[12], *be3 = (const float*)d_in[13];
    const float *W4 = (const float*)d_in[14], *b4  = (const float*)d_in[15];
    float* out = (float*)d_out;

    // Unconditional (no static guards per harness rules): host-side attribute set,
    // not stream-ordered, safe under graph capture. Required for >64KB dynamic LDS.
    hipFuncSetAttribute(reinterpret_cast<const void*>(&edge_mlp),
                        hipFuncAttributeMaxDynamicSharedMemorySize, (int)SMEM_BYTES);

    edge_mlp<<<GRID, BDIM, SMEM_BYTES, stream>>>(nodes, edges,
                                                 W1, b1, g1, be1,
                                                 W2, b2, g2, be2,
                                                 W3, b3, g3, be3,
                                                 W4, b4, out);
}

// Round 7
// 3463.997 us; speedup vs baseline: 1.0010x; 1.0001x over previous
//
#include <hip/hip_runtime.h>

// EdgeNetwork fused MLP on MI355X — register-chained swapped-operand MFMA (bf16 hi/lo split).
// B=8, N=50000, E=200000, D=16, H=128.
// Every layer computes D = W (A-role) x X (B-role) with mfma_f32_16x16x32_bf16, so the
// verified C/D layout (col=lane&15=edge, row=4*(lane>>4)+reg=feature) IS the next layer's
// B-fragment layout: activations never leave registers. fp32 emulated as bf16_hi+bf16_lo,
// 3 MFMAs per product (hh, hl, lh; lo*lo dropped ~2^-17 rel).
// Weights (all 3 layers, hi/lo) staged ONCE per persistent block into 149KB dynamic LDS,
// XOR-swizzled ((j&7)<<4) for minimal-bank-pass ds_read_b128 W-fragment loads.
//
// R6 diagnosis: (512,2)->(512,1) changed NOTHING (VGPR pinned at exactly 128, FETCH 7.18GB,
// WRITE 1.15GB vs 6.4MB legit -> scratch spill traffic confirmed). The cap isn't from
// launch_bounds: with extern __shared__ the backend can't see our 152KB LDS, so its default
// occupancy heuristic targets ~4 waves/EU and caps VGPR=128 by itself.
// R6 fix: explicit __attribute__((amdgpu_waves_per_eu(2,2))) — the direct backend knob.
// 2 waves/EU == our actual launch shape (8 waves, 1 block/CU, LDS-limited), budget 256 VGPR.

#define DEV __device__ __forceinline__

constexpr int NB = 8, NN = 50000, NE = 200000, DD = 16, HH = 128;
constexpr int TILE = 256;                  // edges per block-tile (8 waves x 32)
constexpr int BDIM = 512;
constexpr int GRID = 256;                  // persistent: 1 block per CU
constexpr int NTILE = NB * NE / TILE;      // 6250 exactly
constexpr float LNEPS = 1e-5f;

typedef __attribute__((ext_vector_type(8))) short short8v;  // 8 bf16 (4 VGPRs) MFMA operand
typedef __attribute__((ext_vector_type(4))) float f32x4;    // MFMA accumulator

// LDS carve (shorts): W1 hi|lo 128x32 each (8KB x2), W2 hi|lo 128x128 (32KB x2), W3 same,
// then fp32 params: [3 layers][b,g,be][128] + W4[128] + b4. Total 152580 B < 160KB.
constexpr int W1_HALF = 128 * 32;
constexpr int W2_HALF = 128 * 128;
constexpr size_t SMEM_BYTES = (size_t)(2 * W1_HALF + 4 * W2_HALF) * sizeof(short)
                            + (size_t)(10 * HH + 1) * sizeof(float);

DEV void bsplit(float v, short& h, short& l) {
    unsigned u  = __builtin_bit_cast(unsigned, v);
    unsigned hb = (u + 0x8000u) & 0xFFFF0000u;      // bf16 round-to-nearest (half-up)
    float hf    = __builtin_bit_cast(float, hb);
    h = (short)(hb >> 16);
    float lf    = v - hf;                            // exact residual
    unsigned ul = __builtin_bit_cast(unsigned, lf);
    l = (short)((ul + 0x8000u) >> 16);
}

DEV f32x4 mf(short8v a, short8v b, f32x4 c) {
    return __builtin_amdgcn_mfma_f32_16x16x32_bf16(a, b, c, 0, 0, 0);
}

DEV float tanh_fast(float x) { return 1.0f - 2.0f / (1.0f + __expf(2.0f * x)); }

extern "C" __global__ __launch_bounds__(BDIM)
__attribute__((amdgpu_waves_per_eu(2, 2)))
void edge_mlp(
    const float* __restrict__ nodes, const int* __restrict__ edges,
    const float* __restrict__ W1, const float* __restrict__ b1,
    const float* __restrict__ g1, const float* __restrict__ be1,
    const float* __restrict__ W2, const float* __restrict__ b2,
    const float* __restrict__ g2, const float* __restrict__ be2,
    const float* __restrict__ W3, const float* __restrict__ b3,
    const float* __restrict__ g3, const float* __restrict__ be3,
    const float* __restrict__ W4, const float* __restrict__ b4,
    float* __restrict__ out) {

    extern __shared__ char smem[];
    short* W1h = (short*)smem;
    short* W1l = W1h + W1_HALF;
    short* W2h = W1l + W1_HALF;
    short* W2l = W2h + W2_HALF;
    short* W3h = W2l + W2_HALF;
    short* W3l = W3h + W2_HALF;
    float* P   = (float*)(W3l + W2_HALF);   // [0..2]b1g1be1 [3..5]L2 [6..8]L3 [9]W4 [10*128]b4

    const int tid = threadIdx.x;

    // ---- one-time weight staging (persistent block) ----
    // assumed MFMA k-map (A and B identical): slot i of lane-group g holds
    // k = 32c + 16*(i>>2) + 4g + (i&3); storage index kk = 32c + 8g + 4h2 + e.
    for (int i = tid; i < 32 * 128; i += BDIM) {
        int k = i >> 7, j = i & 127;
        short h, l; bsplit(W1[i], h, l);
        int kk = 8 * ((k >> 2) & 3) + 4 * (k >> 4) + (k & 3);
        W1h[j * 32 + kk] = h;                       // 64B rows: minimal bank passes
        W1l[j * 32 + kk] = l;
    }
    for (int i = tid; i < 128 * 128; i += BDIM) {
        int k = i >> 7, j = i & 127;
        int kk = 32 * (k >> 5) + 8 * ((k >> 2) & 3) + 4 * ((k >> 4) & 1) + (k & 3);
        unsigned off = (unsigned)(j * 256 + kk * 2) ^ ((unsigned)(j & 7) << 4); // byte, swizzled
        short h, l;
        bsplit(W2[i], h, l);
        *(short*)((char*)W2h + off) = h;  *(short*)((char*)W2l + off) = l;
        bsplit(W3[i], h, l);
        *(short*)((char*)W3h + off) = h;  *(short*)((char*)W3l + off) = l;
    }
    if (tid < HH) {
        P[0*HH+tid] = b1[tid]; P[1*HH+tid] = g1[tid]; P[2*HH+tid] = be1[tid];
        P[3*HH+tid] = b2[tid]; P[4*HH+tid] = g2[tid]; P[5*HH+tid] = be2[tid];
        P[6*HH+tid] = b3[tid]; P[7*HH+tid] = g3[tid]; P[8*HH+tid] = be3[tid];
        P[9*HH+tid] = W4[tid];
        if (tid == 0) P[10*HH] = b4[0];
    }
    __syncthreads();

    const int lane = tid & 63;
    const int wv   = tid >> 6;      // wave 0..7
    const int m    = lane & 15;     // A-role: feature row within 16-tile; B-role: edge col
    const int g    = lane >> 4;     // 0..3 k-slot group

    // epilogue: bias + LayerNorm + tanh, in place on acc (f32)
    auto EPI = [&](const float* PB, f32x4 (&A)[2][8]) {
        #pragma unroll
        for (int jt = 0; jt < 8; ++jt) {
            const f32x4 bj = *(const f32x4*)&PB[16 * jt + 4 * g];
            #pragma unroll
            for (int cb = 0; cb < 2; ++cb) {
                A[cb][jt][0] += bj[0]; A[cb][jt][1] += bj[1];
                A[cb][jt][2] += bj[2]; A[cb][jt][3] += bj[3];
            }
        }
        #pragma unroll
        for (int cb = 0; cb < 2; ++cb) {
            float s = 0.f, s2 = 0.f;
            #pragma unroll
            for (int jt = 0; jt < 8; ++jt)
                #pragma unroll
                for (int p = 0; p < 4; ++p) {
                    float v = A[cb][jt][p]; s += v; s2 = fmaf(v, v, s2);
                }
            s  += __shfl_xor(s, 16);  s2 += __shfl_xor(s2, 16);
            s  += __shfl_xor(s, 32);  s2 += __shfl_xor(s2, 32);
            const float mu  = s * (1.f / HH);
            const float var = fmaf(-mu, mu, s2 * (1.f / HH));
            const float rin = rsqrtf(var + LNEPS);
            #pragma unroll
            for (int jt = 0; jt < 8; ++jt) {
                const f32x4 gj = *(const f32x4*)&PB[HH     + 16 * jt + 4 * g];
                const f32x4 bj = *(const f32x4*)&PB[2 * HH + 16 * jt + 4 * g];
                #pragma unroll
                for (int p = 0; p < 4; ++p) {
                    float v = (A[cb][jt][p] - mu) * rin * gj[p] + bj[p];
                    A[cb][jt][p] = tanh_fast(v);
                }
            }
        }
    };

    // acc (post-act) -> next layer's B-fragments: frag[i=4h2+e] = A[cb][2c+h2][e]
    auto TOFRAGS = [&](const f32x4 (&A)[2][8], short8v (&fh)[2][4], short8v (&fl)[2][4]) {
        #pragma unroll
        for (int cb = 0; cb < 2; ++cb)
            #pragma unroll
            for (int c = 0; c < 4; ++c) {
                short8v vh, vl; short h, l;
                bsplit(A[cb][2*c  ][0], h, l); vh[0] = h; vl[0] = l;
                bsplit(A[cb][2*c  ][1], h, l); vh[1] = h; vl[1] = l;
                bsplit(A[cb][2*c  ][2], h, l); vh[2] = h; vl[2] = l;
                bsplit(A[cb][2*c  ][3], h, l); vh[3] = h; vl[3] = l;
                bsplit(A[cb][2*c+1][0], h, l); vh[4] = h; vl[4] = l;
                bsplit(A[cb][2*c+1][1], h, l); vh[5] = h; vl[5] = l;
                bsplit(A[cb][2*c+1][2], h, l); vh[6] = h; vl[6] = l;
                bsplit(A[cb][2*c+1][3], h, l); vh[7] = h; vl[7] = l;
                fh[cb][c] = vh; fl[cb][c] = vl;
            }
    };

    // K=128 GEMM layer: 4 chunks x 8 j-tiles x 2 col-blocks x 3 split-MFMAs
    auto GEMM = [&](const short* Wh, const short* Wl,
                    const short8v (&fh)[2][4], const short8v (&fl)[2][4],
                    f32x4 (&A)[2][8]) {
        #pragma unroll
        for (int cb = 0; cb < 2; ++cb)
            #pragma unroll
            for (int jt = 0; jt < 8; ++jt) A[cb][jt] = (f32x4){0.f, 0.f, 0.f, 0.f};
        #pragma unroll
        for (int c = 0; c < 4; ++c) {
            #pragma unroll
            for (int jt = 0; jt < 8; ++jt) {
                const int jr = 16 * jt + m;
                const unsigned off = (unsigned)(jr * 256 + (32 * c + 8 * g) * 2)
                                   ^ ((unsigned)(jr & 7) << 4);
                const short8v wh = *(const short8v*)((const char*)Wh + off);
                const short8v wl = *(const short8v*)((const char*)Wl + off);
                #pragma unroll
                for (int cb = 0; cb < 2; ++cb) {
                    f32x4 a = A[cb][jt];
                    a = mf(wl, fh[cb][c], a);
                    a = mf(wh, fl[cb][c], a);
                    a = mf(wh, fh[cb][c], a);
                    A[cb][jt] = a;
                }
            }
        }
    };

    // ---- persistent tile loop (no barriers; waves drift and overlap pipes) ----
    for (int t = blockIdx.x; t < NTILE; t += GRID) {
        const int ebase = t * TILE + wv * 32;

        // gather -> layer-1 B-frags, register-direct
        // (slot i<4: endpoint0 feature 4g+(i&3); slot i>=4: endpoint1)
        short8v x1h[2], x1l[2];
        #pragma unroll
        for (int cb = 0; cb < 2; ++cb) {
            const int e = ebase + cb * 16 + m;
            const int2 nv = *(const int2*)(edges + 2 * (size_t)e);   // int32 pairs per harness
            const int b = e / NE;
            const int n0 = min(max(nv.x, 0), NN - 1);                // defensive: fault->absmax
            const int n1 = min(max(nv.y, 0), NN - 1);
            const f32x4 f0 = *(const f32x4*)(nodes + (size_t)(b * NN + n0) * DD + 4 * g);
            const f32x4 f1 = *(const f32x4*)(nodes + (size_t)(b * NN + n1) * DD + 4 * g);
            short8v vh, vl; short h, l;
            bsplit(f0[0], h, l); vh[0] = h; vl[0] = l;
            bsplit(f0[1], h, l); vh[1] = h; vl[1] = l;
            bsplit(f0[2], h, l); vh[2] = h; vl[2] = l;
            bsplit(f0[3], h, l); vh[3] = h; vl[3] = l;
            bsplit(f1[0], h, l); vh[4] = h; vl[4] = l;
            bsplit(f1[1], h, l); vh[5] = h; vl[5] = l;
            bsplit(f1[2], h, l); vh[6] = h; vl[6] = l;
            bsplit(f1[3], h, l); vh[7] = h; vl[7] = l;
            x1h[cb] = vh; x1l[cb] = vl;
        }

        // layer 1 (K=32, one chunk)
        f32x4 acc[2][8];
        #pragma unroll
        for (int jt = 0; jt < 8; ++jt) {
            const int jr = 16 * jt + m;
            const short8v wh = *(const short8v*)&W1h[jr * 32 + 8 * g];
            const short8v wl = *(const short8v*)&W1l[jr * 32 + 8 * g];
            #pragma unroll
            for (int cb = 0; cb < 2; ++cb) {
                f32x4 a = (f32x4){0.f, 0.f, 0.f, 0.f};
                a = mf(wl, x1h[cb], a);
                a = mf(wh, x1l[cb], a);
                a = mf(wh, x1h[cb], a);
                acc[cb][jt] = a;
            }
        }

        short8v xh[2][4], xl[2][4];
        EPI(P + 0 * 3 * HH, acc);
        TOFRAGS(acc, xh, xl);
        GEMM(W2h, W2l, xh, xl, acc);      // layer 2
        EPI(P + 1 * 3 * HH, acc);
        TOFRAGS(acc, xh, xl);
        GEMM(W3h, W3l, xh, xl, acc);      // layer 3
        EPI(P + 2 * 3 * HH, acc);

        // layer 4: per-lane partial dot over its 32 features, reduce over g-groups, sigmoid
        const float bb4 = P[10 * HH];
        #pragma unroll
        for (int cb = 0; cb < 2; ++cb) {
            float s = 0.f;
            #pragma unroll
            for (int jt = 0; jt < 8; ++jt) {
                const f32x4 w4v = *(const f32x4*)&P[9 * HH + 16 * jt + 4 * g];
                s = fmaf(acc[cb][jt][0], w4v[0], s);
                s = fmaf(acc[cb][jt][1], w4v[1], s);
                s = fmaf(acc[cb][jt][2], w4v[2], s);
                s = fmaf(acc[cb][jt][3], w4v[3], s);
            }
            s += __shfl_xor(s, 16);
            s += __shfl_xor(s, 32);
            if (g == 0) out[ebase + cb * 16 + m] = 1.f / (1.f + __expf(-(s + bb4)));
        }
    }
}

extern "C" void kernel_launch(void* const* d_in, const int* in_sizes, int n_in,
                              void* d_out, int out_size, void* d_ws, size_t ws_size,
                              hipStream_t stream) {
    (void)in_sizes; (void)n_in; (void)d_ws; (void)ws_size; (void)out_size;
    const float* nodes = (const float*)d_in[0];
    const int*   edges = (const int*)d_in[1];     // harness: integer inputs arrive as int32
    const float *W1 = (const float*)d_in[2],  *b1  = (const float*)d_in[3];
    const float *g1 = (const float*)d_in[4],  *be1 = (const float*)d_in[5];
    const float *W2 = (const float*)d_in[6],  *b2  = (const float*)d_in[7];
    const float *g2 = (const float*)d_in[8],  *be2 = (const float*)d_in[9];
    const float *W3 = (const float*)d_in[10], *b3  = (const float*)d_in[11];
    const float *g3 = (const float*)d_in[12], *be3 = (const float*)d_in[13];
    const float *W4 = (const float*)d_in[14], *b4  = (const float*)d_in[15];
    float* out = (float*)d_out;

    // Unconditional (no static guards per harness rules): host-side attribute set,
    // not stream-ordered, safe under graph capture. Required for >64KB dynamic LDS.
    hipFuncSetAttribute(reinterpret_cast<const void*>(&edge_mlp),
                        hipFuncAttributeMaxDynamicSharedMemorySize, (int)SMEM_BYTES);

    edge_mlp<<<GRID, BDIM, SMEM_BYTES, stream>>>(nodes, edges,
                                                 W1, b1, g1, be1,
                                                 W2, b2, g2, be2,
                                                 W3, b3, g3, be3,
                                                 W4, b4, out);
}

// Round 8
// 3348.129 us; speedup vs baseline: 1.0356x; 1.0346x over previous
//
#include <hip/hip_runtime.h>

// EdgeNetwork fused MLP on MI355X — register-chained swapped-operand MFMA (bf16 hi/lo split).
// B=8, N=50000, E=200000, D=16, H=128.
// D = W(A-role) x X(B-role) per layer with mfma_f32_16x16x32_bf16: the C/D layout
// (col=lane&15=edge, row=4*(lane>>4)+reg=feature) IS the next layer's B-fragment layout,
// so activations chain in registers. fp32 = bf16_hi+lo, 3 MFMAs/product.
// Weights staged once per persistent block into 149KB dynamic LDS (XOR-swizzled).
//
// HISTORY: R5/R6/R7 all showed dur==hbm_bytes/BW with 7.18GB FETCH + 1.15GB WRITE of
// scratch traffic, VGPR pinned at exactly 128 regardless of launch_bounds (512,2)->(512,1)
// or amdgpu_waves_per_eu(2,2) (R7: SGPR 64->112 proves the attribute applied; VGPR and
// traffic unchanged). Conclusion: NOT budget-driven spill — the per-tile arrays
// (acc[2][8], frags[2][4]) captured by reference into lambdas were never SROA-promoted;
// they lived in scratch as allocas (rule-#20 family). Every MFMA operand access was a
// scratch read -> 6.9GB re-read.
// R8 FIX: no lambdas, no arrays. Every accumulator/fragment is an individually NAMED
// variable via macros — allocas cannot exist. waves_per_eu(2,2) kept: real register
// demand is now ~170-200 VGPR and the default heuristic's 128 cap would cause true spill.

#define DEV __device__ __forceinline__

constexpr int NB = 8, NN = 50000, NE = 200000, DD = 16, HH = 128;
constexpr int TILE = 256;                  // edges per block-tile (8 waves x 32)
constexpr int BDIM = 512;
constexpr int GRID = 256;                  // persistent: 1 block per CU
constexpr int NTILE = NB * NE / TILE;      // 6250 exactly
constexpr float LNEPS = 1e-5f;

typedef __attribute__((ext_vector_type(8))) short short8v;  // 8 bf16 MFMA operand
typedef __attribute__((ext_vector_type(4))) float f32x4;    // MFMA accumulator

constexpr int W1_HALF = 128 * 32;
constexpr int W2_HALF = 128 * 128;
constexpr size_t SMEM_BYTES = (size_t)(2 * W1_HALF + 4 * W2_HALF) * sizeof(short)
                            + (size_t)(10 * HH + 1) * sizeof(float);

DEV void bsplit(float v, short& h, short& l) {
    unsigned u  = __builtin_bit_cast(unsigned, v);
    unsigned hb = (u + 0x8000u) & 0xFFFF0000u;      // bf16 RTN (half-up)
    float hf    = __builtin_bit_cast(float, hb);
    h = (short)(hb >> 16);
    float lf    = v - hf;                            // exact residual
    unsigned ul = __builtin_bit_cast(unsigned, lf);
    l = (short)((ul + 0x8000u) >> 16);
}

DEV f32x4 mf(short8v a, short8v b, f32x4 c) {
    return __builtin_amdgcn_mfma_f32_16x16x32_bf16(a, b, c, 0, 0, 0);
}

DEV float tanh_fast(float x) { return 1.0f - 2.0f / (1.0f + __expf(2.0f * x)); }

#define ZERO4 ((f32x4){0.f, 0.f, 0.f, 0.f})

// ---- straight-line code generators (no arrays -> no allocas -> no scratch) ----

#define GATHER(cb, VH, VL) { \
    const int e = ebase + (cb) * 16 + m; \
    const int2 nv = *(const int2*)(edges + 2 * (size_t)e); \
    const int b = e / NE; \
    const int n0 = min(max(nv.x, 0), NN - 1); \
    const int n1 = min(max(nv.y, 0), NN - 1); \
    const f32x4 f0 = *(const f32x4*)(nodes + (size_t)(b * NN + n0) * DD + 4 * g); \
    const f32x4 f1 = *(const f32x4*)(nodes + (size_t)(b * NN + n1) * DD + 4 * g); \
    short h, l; short8v vh, vl; \
    bsplit(f0[0], h, l); vh[0] = h; vl[0] = l; \
    bsplit(f0[1], h, l); vh[1] = h; vl[1] = l; \
    bsplit(f0[2], h, l); vh[2] = h; vl[2] = l; \
    bsplit(f0[3], h, l); vh[3] = h; vl[3] = l; \
    bsplit(f1[0], h, l); vh[4] = h; vl[4] = l; \
    bsplit(f1[1], h, l); vh[5] = h; vl[5] = l; \
    bsplit(f1[2], h, l); vh[6] = h; vl[6] = l; \
    bsplit(f1[3], h, l); vh[7] = h; vl[7] = l; \
    VH = vh; VL = vl; }

#define L1JT(jt) { \
    const int jr = 16 * jt + m; \
    const short8v wh = *(const short8v*)&W1h[jr * 32 + 8 * g]; \
    const short8v wl = *(const short8v*)&W1l[jr * 32 + 8 * g]; \
    f32x4 a = ZERO4; a = mf(wl, X1H0, a); a = mf(wh, X1L0, a); a = mf(wh, X1H0, a); AC0##jt = a; \
    f32x4 b = ZERO4; b = mf(wl, X1H1, b); b = mf(wh, X1L1, b); b = mf(wh, X1H1, b); AC1##jt = b; }

#define EPI_ADDSUM(X, jt) { \
    const f32x4 bj = *(const f32x4*)&PB[16 * jt + 4 * g]; \
    X[0] += bj[0]; X[1] += bj[1]; X[2] += bj[2]; X[3] += bj[3]; \
    s += X[0] + X[1] + X[2] + X[3]; \
    s2 = fmaf(X[0], X[0], s2); s2 = fmaf(X[1], X[1], s2); \
    s2 = fmaf(X[2], X[2], s2); s2 = fmaf(X[3], X[3], s2); }

#define EPI_NORM(X, jt) { \
    const f32x4 gj = *(const f32x4*)&PB[HH + 16 * jt + 4 * g]; \
    const f32x4 bb = *(const f32x4*)&PB[2 * HH + 16 * jt + 4 * g]; \
    X[0] = tanh_fast((X[0] - mu) * rin * gj[0] + bb[0]); \
    X[1] = tanh_fast((X[1] - mu) * rin * gj[1] + bb[1]); \
    X[2] = tanh_fast((X[2] - mu) * rin * gj[2] + bb[2]); \
    X[3] = tanh_fast((X[3] - mu) * rin * gj[3] + bb[3]); }

#define EPI_CB(cb) { \
    float s = 0.f, s2 = 0.f; \
    EPI_ADDSUM(AC##cb##0, 0) EPI_ADDSUM(AC##cb##1, 1) \
    EPI_ADDSUM(AC##cb##2, 2) EPI_ADDSUM(AC##cb##3, 3) \
    EPI_ADDSUM(AC##cb##4, 4) EPI_ADDSUM(AC##cb##5, 5) \
    EPI_ADDSUM(AC##cb##6, 6) EPI_ADDSUM(AC##cb##7, 7) \
    s += __shfl_xor(s, 16); s2 += __shfl_xor(s2, 16); \
    s += __shfl_xor(s, 32); s2 += __shfl_xor(s2, 32); \
    const float mu  = s * (1.f / HH); \
    const float var = fmaf(-mu, mu, s2 * (1.f / HH)); \
    const float rin = rsqrtf(var + LNEPS); \
    EPI_NORM(AC##cb##0, 0) EPI_NORM(AC##cb##1, 1) \
    EPI_NORM(AC##cb##2, 2) EPI_NORM(AC##cb##3, 3) \
    EPI_NORM(AC##cb##4, 4) EPI_NORM(AC##cb##5, 5) \
    EPI_NORM(AC##cb##6, 6) EPI_NORM(AC##cb##7, 7) }

// next-layer B-frag: slot i=4*h2+e <- AC[cb][2c+h2][e]
#define TOF(cb, c, SA, SB) { \
    short h, l; short8v vh, vl; \
    bsplit(SA[0], h, l); vh[0] = h; vl[0] = l; \
    bsplit(SA[1], h, l); vh[1] = h; vl[1] = l; \
    bsplit(SA[2], h, l); vh[2] = h; vl[2] = l; \
    bsplit(SA[3], h, l); vh[3] = h; vl[3] = l; \
    bsplit(SB[0], h, l); vh[4] = h; vl[4] = l; \
    bsplit(SB[1], h, l); vh[5] = h; vl[5] = l; \
    bsplit(SB[2], h, l); vh[6] = h; vl[6] = l; \
    bsplit(SB[3], h, l); vh[7] = h; vl[7] = l; \
    FH##cb##c = vh; FL##cb##c = vl; }

#define TOFRAGS_ALL \
    TOF(0, 0, AC00, AC01) TOF(0, 1, AC02, AC03) TOF(0, 2, AC04, AC05) TOF(0, 3, AC06, AC07) \
    TOF(1, 0, AC10, AC11) TOF(1, 1, AC12, AC13) TOF(1, 2, AC14, AC15) TOF(1, 3, AC16, AC17)

#define ZACC \
    AC00 = ZERO4; AC01 = ZERO4; AC02 = ZERO4; AC03 = ZERO4; \
    AC04 = ZERO4; AC05 = ZERO4; AC06 = ZERO4; AC07 = ZERO4; \
    AC10 = ZERO4; AC11 = ZERO4; AC12 = ZERO4; AC13 = ZERO4; \
    AC14 = ZERO4; AC15 = ZERO4; AC16 = ZERO4; AC17 = ZERO4;

#define GSTEP(c, jt) { \
    const int jr = 16 * jt + m; \
    const unsigned off = (unsigned)(jr * 256 + (32 * c + 8 * g) * 2) \
                       ^ ((unsigned)(jr & 7) << 4); \
    const short8v wh = *(const short8v*)((const char*)Wh + off); \
    const short8v wl = *(const short8v*)((const char*)Wl + off); \
    AC0##jt = mf(wl, FH0##c, AC0##jt); \
    AC0##jt = mf(wh, FL0##c, AC0##jt); \
    AC0##jt = mf(wh, FH0##c, AC0##jt); \
    AC1##jt = mf(wl, FH1##c, AC1##jt); \
    AC1##jt = mf(wh, FL1##c, AC1##jt); \
    AC1##jt = mf(wh, FH1##c, AC1##jt); }

#define GLAYER \
    ZACC \
    GSTEP(0, 0) GSTEP(0, 1) GSTEP(0, 2) GSTEP(0, 3) \
    GSTEP(0, 4) GSTEP(0, 5) GSTEP(0, 6) GSTEP(0, 7) \
    GSTEP(1, 0) GSTEP(1, 1) GSTEP(1, 2) GSTEP(1, 3) \
    GSTEP(1, 4) GSTEP(1, 5) GSTEP(1, 6) GSTEP(1, 7) \
    GSTEP(2, 0) GSTEP(2, 1) GSTEP(2, 2) GSTEP(2, 3) \
    GSTEP(2, 4) GSTEP(2, 5) GSTEP(2, 6) GSTEP(2, 7) \
    GSTEP(3, 0) GSTEP(3, 1) GSTEP(3, 2) GSTEP(3, 3) \
    GSTEP(3, 4) GSTEP(3, 5) GSTEP(3, 6) GSTEP(3, 7)

#define L4JT(cb, jt) { \
    const f32x4 w4v = *(const f32x4*)&P[9 * HH + 16 * jt + 4 * g]; \
    s = fmaf(AC##cb##jt[0], w4v[0], s); s = fmaf(AC##cb##jt[1], w4v[1], s); \
    s = fmaf(AC##cb##jt[2], w4v[2], s); s = fmaf(AC##cb##jt[3], w4v[3], s); }

#define L4DOT(cb) { \
    float s = 0.f; \
    L4JT(cb, 0) L4JT(cb, 1) L4JT(cb, 2) L4JT(cb, 3) \
    L4JT(cb, 4) L4JT(cb, 5) L4JT(cb, 6) L4JT(cb, 7) \
    s += __shfl_xor(s, 16); \
    s += __shfl_xor(s, 32); \
    if (g == 0) out[ebase + (cb) * 16 + m] = 1.f / (1.f + __expf(-(s + bb4))); }

extern "C" __global__ __launch_bounds__(BDIM)
__attribute__((amdgpu_waves_per_eu(2, 2)))
void edge_mlp(
    const float* __restrict__ nodes, const int* __restrict__ edges,
    const float* __restrict__ W1, const float* __restrict__ b1,
    const float* __restrict__ g1, const float* __restrict__ be1,
    const float* __restrict__ W2, const float* __restrict__ b2,
    const float* __restrict__ g2, const float* __restrict__ be2,
    const float* __restrict__ W3, const float* __restrict__ b3,
    const float* __restrict__ g3, const float* __restrict__ be3,
    const float* __restrict__ W4, const float* __restrict__ b4,
    float* __restrict__ out) {

    extern __shared__ char smem[];
    short* W1h = (short*)smem;
    short* W1l = W1h + W1_HALF;
    short* W2h = W1l + W1_HALF;
    short* W2l = W2h + W2_HALF;
    short* W3h = W2l + W2_HALF;
    short* W3l = W3h + W2_HALF;
    float* P   = (float*)(W3l + W2_HALF);   // [0..2]=L1 b,g,be  [3..5]=L2  [6..8]=L3  [9]=W4  [10*128]=b4

    const int tid = threadIdx.x;

    // ---- one-time weight staging: k = 32c+16h2+4g+e -> kk = 32c+8g+4h2+e ----
    for (int i = tid; i < 32 * 128; i += BDIM) {
        int k = i >> 7, j = i & 127;
        short h, l; bsplit(W1[i], h, l);
        int kk = 8 * ((k >> 2) & 3) + 4 * (k >> 4) + (k & 3);
        W1h[j * 32 + kk] = h;
        W1l[j * 32 + kk] = l;
    }
    for (int i = tid; i < 128 * 128; i += BDIM) {
        int k = i >> 7, j = i & 127;
        int kk = 32 * (k >> 5) + 8 * ((k >> 2) & 3) + 4 * ((k >> 4) & 1) + (k & 3);
        unsigned off = (unsigned)(j * 256 + kk * 2) ^ ((unsigned)(j & 7) << 4);
        short h, l;
        bsplit(W2[i], h, l);
        *(short*)((char*)W2h + off) = h;  *(short*)((char*)W2l + off) = l;
        bsplit(W3[i], h, l);
        *(short*)((char*)W3h + off) = h;  *(short*)((char*)W3l + off) = l;
    }
    if (tid < HH) {
        P[0*HH+tid] = b1[tid]; P[1*HH+tid] = g1[tid]; P[2*HH+tid] = be1[tid];
        P[3*HH+tid] = b2[tid]; P[4*HH+tid] = g2[tid]; P[5*HH+tid] = be2[tid];
        P[6*HH+tid] = b3[tid]; P[7*HH+tid] = g3[tid]; P[8*HH+tid] = be3[tid];
        P[9*HH+tid] = W4[tid];
        if (tid == 0) P[10*HH] = b4[0];
    }
    __syncthreads();

    const int lane = tid & 63;
    const int wv   = tid >> 6;
    const int m    = lane & 15;     // A-role: feature row in 16-tile; B-role: edge col
    const int g    = lane >> 4;     // k-slot group

    for (int t = blockIdx.x; t < NTILE; t += GRID) {
        const int ebase = t * TILE + wv * 32;

        // all state: named registers only (R8: no arrays -> no allocas -> no scratch)
        f32x4 AC00, AC01, AC02, AC03, AC04, AC05, AC06, AC07;
        f32x4 AC10, AC11, AC12, AC13, AC14, AC15, AC16, AC17;
        short8v FH00, FH01, FH02, FH03, FH10, FH11, FH12, FH13;
        short8v FL00, FL01, FL02, FL03, FL10, FL11, FL12, FL13;
        short8v X1H0, X1L0, X1H1, X1L1;

        GATHER(0, X1H0, X1L0)
        GATHER(1, X1H1, X1L1)

        // layer 1 (K=32)
        L1JT(0) L1JT(1) L1JT(2) L1JT(3) L1JT(4) L1JT(5) L1JT(6) L1JT(7)
        { const float* PB = P;          EPI_CB(0) EPI_CB(1) }
        TOFRAGS_ALL

        // layer 2 (K=128)
        { const short* Wh = W2h; const short* Wl = W2l; GLAYER }
        { const float* PB = P + 3 * HH; EPI_CB(0) EPI_CB(1) }
        TOFRAGS_ALL

        // layer 3 (K=128)
        { const short* Wh = W3h; const short* Wl = W3l; GLAYER }
        { const float* PB = P + 6 * HH; EPI_CB(0) EPI_CB(1) }

        // layer 4 + sigmoid
        const float bb4 = P[10 * HH];
        L4DOT(0)
        L4DOT(1)
    }
}

extern "C" void kernel_launch(void* const* d_in, const int* in_sizes, int n_in,
                              void* d_out, int out_size, void* d_ws, size_t ws_size,
                              hipStream_t stream) {
    (void)in_sizes; (void)n_in; (void)d_ws; (void)ws_size; (void)out_size;
    const float* nodes = (const float*)d_in[0];
    const int*   edges = (const int*)d_in[1];     // harness: integer inputs arrive as int32
    const float *W1 = (const float*)d_in[2],  *b1  = (const float*)d_in[3];
    const float *g1 = (const float*)d_in[4],  *be1 = (const float*)d_in[5];
    const float *W2 = (const float*)d_in[6],  *b2  = (const float*)d_in[7];
    const float *g2 = (const float*)d_in[8],  *be2 = (const float*)d_in[9];
    const float *W3 = (const float*)d_in[10], *b3  = (const float*)d_in[11];
    const float *g3 = (const float*)d_in[12], *be3 = (const float*)d_in[13];
    const float *W4 = (const float*)d_in[14], *b4  = (const float*)d_in[15];
    float* out = (float*)d_out;

    hipFuncSetAttribute(reinterpret_cast<const void*>(&edge_mlp),
                        hipFuncAttributeMaxDynamicSharedMemorySize, (int)SMEM_BYTES);

    edge_mlp<<<GRID, BDIM, SMEM_BYTES, stream>>>(nodes, edges,
                                                 W1, b1, g1, be1,
                                                 W2, b2, g2, be2,
                                                 W3, b3, g3, be3,
                                                 W4, b4, out);
}